// Round 15
// baseline (107.756 us; speedup 1.0000x reference)
//
#include <hip/hip_runtime.h>

#define L 2048
#define H 8
#define S 128
#define B 8
#define HS 1024

// ============ KA: fused {per-b E,Z prefix-scan} + partial_q ============
// grid (B, 16) = 128 blocks x 512 threads. j-chunks of 128.
__global__ __launch_bounds__(512) void kA_prep_qpart(const float* __restrict__ W,
                                                     const float* __restrict__ x,
                                                     float* __restrict__ Eb,
                                                     float* __restrict__ Zb,
                                                     float* __restrict__ partial_q,
                                                     unsigned* __restrict__ counters) {
  const int b = blockIdx.x, jc = blockIdx.y;
  const int t = threadIdx.x;
  // zero 72 padded gate slots (64 level-1 + 8 level-2), 64B stride
  if (b == 0 && jc == 0 && t < 72) counters[t * 16] = 0u;

  __shared__ float ew[128][H];       // 4 KB
  __shared__ float part[16][H][S];   // 64 KB
  __shared__ float tot[512];         // 2 KB

  const int base = jc * 128;
  const int dhi = L - 1 - base;
#pragma unroll
  for (int k = 0; k < 2; ++k) {
    const int idx = t + k * 512;     // [0,1024): i = idx>>3, h = idx&7
    const int i = idx >> 3, h = idx & 7;
    ew[i][h] = expf(W[(size_t)(dhi - i) * H + h]);
  }

  // --- per-b full prefix scan for one h (8 blocks per b) ---
  if (jc < H) {
    const int h = jc;
    const int d0 = t * 4;
    float e[4];
    float run = 0.f;
#pragma unroll
    for (int k = 0; k < 4; ++k) {
      float v = expf(W[(size_t)(d0 + k) * H + h]);
      e[k] = v; run += v;
    }
    tot[t] = run;
    __syncthreads();
    for (int off = 1; off < 512; off <<= 1) {
      float v = (t >= off) ? tot[t - off] : 0.f;
      __syncthreads();
      tot[t] += v;
      __syncthreads();
    }
    float c = (t == 0) ? 0.f : tot[t - 1];
    const size_t ebase = (size_t)(b * H + h) * L;
#pragma unroll
    for (int k = 0; k < 4; ++k) {
      c += e[k];
      Eb[ebase + d0 + k] = e[k];
      Zb[ebase + d0 + k] = c;
    }
  }
  __syncthreads();

  // --- partial_q main loop: 16 row-groups x 8 rows each ---
  const int s4 = t & 31;
  const int r = t >> 5;
  const float4* __restrict__ x4 = (const float4*)(x + (size_t)b * L * S);
  float4 acc[H];
#pragma unroll
  for (int h = 0; h < H; ++h) acc[h] = make_float4(0.f, 0.f, 0.f, 0.f);
#pragma unroll
  for (int k = 0; k < 8; ++k) {
    const int ll = k * 16 + r;
    const int l = base + ll;
    const float4 xv = x4[(size_t)l * 32 + s4];
#pragma unroll
    for (int h = 0; h < H; ++h) {
      const float w = ew[ll][h];
      acc[h].x += w * xv.x; acc[h].y += w * xv.y;
      acc[h].z += w * xv.z; acc[h].w += w * xv.w;
    }
  }
#pragma unroll
  for (int h = 0; h < H; ++h) {
    part[r][h][s4 * 4 + 0] = acc[h].x;
    part[r][h][s4 * 4 + 1] = acc[h].y;
    part[r][h][s4 * 4 + 2] = acc[h].z;
    part[r][h][s4 * 4 + 3] = acc[h].w;
  }
  __syncthreads();
#pragma unroll
  for (int k = 0; k < 2; ++k) {
    const int idx = t + k * 512;           // h*S + s
    const int h = idx >> 7, s = idx & 127;
    float sm = 0.f;
#pragma unroll
    for (int rr = 0; rr < 16; ++rr) sm += part[rr][h][s];
    partial_q[((size_t)b * 16 + jc) * HS + idx] = sm;
  }
}

// ============ KB: all-batch GEMV over one A-chunk ============
// grid (8 ec, 16 dc) = 128 blocks x 512 threads.
__global__ __launch_bounds__(512) void kB_v(const float* __restrict__ partial_q,
                                            const float* __restrict__ Zb,
                                            const float* __restrict__ A,
                                            float* __restrict__ partial_v) {
  const int ebase = blockIdx.x * 128;
  const int dc = blockIdx.y;
  const int dbase = dc * 64;
  const int t = threadIdx.x;
  __shared__ float ql[8][64];
  __shared__ float p2[4][8][128];
  const float invZ = 1.f / Zb[(size_t)(dc >> 1) * L + (L - 1)];   // b=0 copy; h = dc>>1
  {
    const int bb = t >> 6, dl = t & 63;
    const float* __restrict__ pq = partial_q + ((size_t)bb * 16) * HS + dbase + dl;
    float a0 = 0.f, a1 = 0.f, a2 = 0.f, a3 = 0.f;
#pragma unroll
    for (int j4 = 0; j4 < 16; j4 += 4) {
      a0 += pq[(size_t)(j4 + 0) * HS];
      a1 += pq[(size_t)(j4 + 1) * HS];
      a2 += pq[(size_t)(j4 + 2) * HS];
      a3 += pq[(size_t)(j4 + 3) * HS];
    }
    ql[bb][dl] = ((a0 + a1) + (a2 + a3)) * invZ;
  }
  __syncthreads();
  const int el = t & 127, dg = t >> 7;
  const int e = ebase + el;
  const float* __restrict__ Ab = A + (size_t)(dbase + dg * 16) * HS + e;
  float acc[8] = {0.f, 0.f, 0.f, 0.f, 0.f, 0.f, 0.f, 0.f};
#pragma unroll 4
  for (int dd = 0; dd < 16; ++dd) {
    const float a = Ab[(size_t)dd * HS];
    const int d = dg * 16 + dd;
    acc[0] += ql[0][d] * a;
    acc[1] += ql[1][d] * a;
    acc[2] += ql[2][d] * a;
    acc[3] += ql[3][d] * a;
    acc[4] += ql[4][d] * a;
    acc[5] += ql[5][d] * a;
    acc[6] += ql[6][d] * a;
    acc[7] += ql[7][d] * a;
  }
#pragma unroll
  for (int bb = 0; bb < 8; ++bb) p2[dg][bb][el] = acc[bb];
  __syncthreads();
#pragma unroll
  for (int k = 0; k < 2; ++k) {
    const int idx = t + k * 512;
    const int bb = idx >> 7, el2 = idx & 127;
    partial_v[((size_t)bb * 16 + dc) * HS + ebase + el2] =
        (p2[0][bb][el2] + p2[1][bb][el2]) + (p2[2][bb][el2] + p2[3][bb][el2]);
  }
}

// ============ KC: fused v-reduce + u ============
// grid (B, 16) = 128 blocks x 512 threads -> XCD b.
__global__ __launch_bounds__(512) void kC_u(const float* __restrict__ x,
                                            const float* __restrict__ partial_v,
                                            float* __restrict__ u_pad) {
  const int b = blockIdx.x, jc = blockIdx.y;
  const int t = threadIdx.x;
  __shared__ float vs[HS];
  __shared__ float up[4][H][128];
#pragma unroll
  for (int k = 0; k < 2; ++k) {
    const int i = t + k * 512;
    float a0 = 0.f, a1 = 0.f, a2 = 0.f, a3 = 0.f;
#pragma unroll
    for (int dcc = 0; dcc < 16; dcc += 4) {
      a0 += partial_v[((size_t)b * 16 + dcc + 0) * HS + i];
      a1 += partial_v[((size_t)b * 16 + dcc + 1) * HS + i];
      a2 += partial_v[((size_t)b * 16 + dcc + 2) * HS + i];
      a3 += partial_v[((size_t)b * 16 + dcc + 3) * HS + i];
    }
    vs[i] = (a0 + a1) + (a2 + a3);
  }
  __syncthreads();
  const int jl = t & 127, sq = t >> 7;
  const int j = jc * 128 + jl;
  const float4* __restrict__ xr = (const float4*)(x + ((size_t)b * L + j) * S) + sq * 8;
  float4 xv[8];
#pragma unroll
  for (int i = 0; i < 8; ++i) xv[i] = xr[i];
  float acc[H];
#pragma unroll
  for (int h = 0; h < H; ++h) {
    const float4* __restrict__ vv = (const float4*)(vs + h * S + sq * 32);
    float a = 0.f;
#pragma unroll
    for (int i = 0; i < 8; ++i) {
      const float4 w = vv[i];
      a += xv[i].x * w.x + xv[i].y * w.y + xv[i].z * w.z + xv[i].w * w.w;
    }
    acc[h] = a;
  }
#pragma unroll
  for (int h = 0; h < H; ++h) up[sq][h][jl] = acc[h];
  __syncthreads();
#pragma unroll
  for (int k = 0; k < 2; ++k) {
    const int idx = t + k * 512;
    const int h = idx >> 7, j2 = idx & 127;
    const float sv = (up[0][h][j2] + up[1][h][j2]) + (up[2][h][j2] + up[3][h][j2]);
    const size_t rowbase = (size_t)(b * H + h) * (2 * L);
    u_pad[rowbase + jc * 128 + j2] = 0.f;        // zero pad (front half)
    u_pad[rowbase + L + jc * 128 + j2] = sv;
  }
}

// ============ KDF: uniform conv tiles + two-level padded per-b gate -> softmax + out ============
// grid (B, 72) = 576 blocks x 512 threads -> batch b pinned to XCD b.
// Conv part IDENTICAL to r13 kD (uniform 256-wide d-tiles, balanced).
// Gate: 8 groups of 9 blocks per b; padded 64B counters (no same-line RMW pileup).
// Winner block: sum dtt slices -> softmax -> weighted x sum -> out[b].
__global__ __launch_bounds__(512) void kDF_out(const float* __restrict__ x,
                                               const float* __restrict__ u_pad,
                                               const float* __restrict__ Eb,
                                               const float* __restrict__ Zb,
                                               float* __restrict__ partial_s,
                                               unsigned* __restrict__ counters,
                                               float* __restrict__ out) {
  const int b = blockIdx.x;
  const int rr = blockIdx.y;
  int lt = 0, c = 0;
  while (c + (lt / 2 + 1) <= rr) { c += lt / 2 + 1; ++lt; }
  const int dtt = rr - c;
  const int l0 = lt * 128;
  const int t = threadIdx.x;
  const int tsub = t & 31;
  const int h = (t >> 5) & 7;
  const int dh = t >> 8;
  const int dbase = dtt * 256 + dh * 128;
  const int Lb = l0 + tsub * 4;

  __shared__ float sred[2][H][128];   // 8 KB
  __shared__ float ep[L];             // 8 KB (winner)
  __shared__ float red[512];          // 2 KB
  __shared__ float part[16][S];       // 8 KB

  {
    const float* __restrict__ ur = u_pad + (size_t)(b * H + h) * (2 * L) + L;
    const float4* __restrict__ Eh4 = (const float4*)(Eb + (size_t)(b * H + h) * L);
    float acc0 = 0.f, acc1 = 0.f, acc2 = 0.f, acc3 = 0.f;
    float4 lo = *(const float4*)(ur + Lb - dbase - 4);   // zero-pad covers d>l
    float4 hi = *(const float4*)(ur + Lb - dbase);
#pragma unroll 4
    for (int dd = 0; dd < 128; dd += 4) {
      const int d0 = dbase + dd;
      float4 ev  = Eh4[d0 >> 2];                        // wave-uniform -> scalar load
      float4 nlo = *(const float4*)(ur + Lb - d0 - 8);
      acc0 += ev.x * hi.x; acc1 += ev.x * hi.y; acc2 += ev.x * hi.z; acc3 += ev.x * hi.w;
      acc0 += ev.y * lo.w; acc1 += ev.y * hi.x; acc2 += ev.y * hi.y; acc3 += ev.y * hi.z;
      acc0 += ev.z * lo.z; acc1 += ev.z * lo.w; acc2 += ev.z * hi.x; acc3 += ev.z * hi.y;
      acc0 += ev.w * lo.y; acc1 += ev.w * lo.z; acc2 += ev.w * lo.w; acc3 += ev.w * hi.x;
      hi = lo; lo = nlo;
    }
    const float4 zv = *(const float4*)&Zb[(size_t)(b * H + h) * L + Lb];
    sred[dh][h][tsub * 4 + 0] = acc0 / zv.x;
    sred[dh][h][tsub * 4 + 1] = acc1 / zv.y;
    sred[dh][h][tsub * 4 + 2] = acc2 / zv.z;
    sred[dh][h][tsub * 4 + 3] = acc3 / zv.w;
    __syncthreads();
    if (t < 128) {
      float sc = 0.f;
#pragma unroll
      for (int hh = 0; hh < H; ++hh) sc += sred[0][hh][t] + sred[1][hh][t];
      partial_s[((size_t)b * 8 + dtt) * L + l0 + t] = sc;
    }
  }

  // --- two-level padded gate (groups of 9 -> per-b level 2) ---
  __threadfence();
  __syncthreads();
  __shared__ unsigned lastFlag;
  if (t == 0) {
    unsigned lf = 0u;
    const int g = rr / 9;                       // 8 groups of 9
    const unsigned o1 = atomicAdd(&counters[(b * 8 + g) * 16], 1u);
    if (o1 == 8u) {                             // last of this group of 9
      const unsigned o2 = atomicAdd(&counters[(64 + b) * 16], 1u);
      lf = (o2 == 7u) ? 1u : 0u;                // last group-winner of batch b
    }
    lastFlag = lf;
  }
  __syncthreads();
  if (!lastFlag) return;
  __threadfence();   // acquire-side ordering for partial_s reads

  // --- winner: scores = sum_dtt partial_s; softmax -> ep ---
  const int l4 = t * 4;
  const int ltq = t >> 6;                 // floor(lt/2), lt = (4t)>>7
  float sc[4] = {0.f, 0.f, 0.f, 0.f};
  for (int d2 = 0; d2 <= ltq; ++d2) {
    const float4 a = *(const float4*)(partial_s + ((size_t)b * 8 + d2) * L + l4);
    sc[0] += a.x; sc[1] += a.y; sc[2] += a.z; sc[3] += a.w;
  }
  if (t == 511) sc[3] = -3.4e38f;         // l = 2047 excluded
  float mx = fmaxf(fmaxf(sc[0], sc[1]), fmaxf(sc[2], sc[3]));
  red[t] = mx;
  __syncthreads();
  for (int off = 256; off > 0; off >>= 1) {
    if (t < off) red[t] = fmaxf(red[t], red[t + off]);
    __syncthreads();
  }
  mx = red[0];
  __syncthreads();
  float e0 = expf(sc[0] - mx), e1 = expf(sc[1] - mx);
  float e2 = expf(sc[2] - mx), e3 = expf(sc[3] - mx);   // l=2047 -> 0
  red[t] = (e0 + e1) + (e2 + e3);
  __syncthreads();
  for (int off = 256; off > 0; off >>= 1) {
    if (t < off) red[t] += red[t + off];
    __syncthreads();
  }
  const float inv = 1.f / red[0];
  ep[l4 + 0] = e0 * inv;
  ep[l4 + 1] = e1 * inv;
  ep[l4 + 2] = e2 * inv;
  ep[l4 + 3] = e3 * inv;
  __syncthreads();

  // --- winner: out[b,s] = sum_l ep[l] * x[b,l,s] ---
  const int s4 = t & 31;
  const int r = t >> 5;                   // 16 l-groups
  const float4* __restrict__ x4 = (const float4*)(x + (size_t)b * L * S);
  float4 acc = make_float4(0.f, 0.f, 0.f, 0.f);
  for (int k = 0; k < 128; ++k) {
    const int l = k * 16 + r;
    const float w = ep[l];
    const float4 xv = x4[(size_t)l * 32 + s4];
    acc.x += w * xv.x; acc.y += w * xv.y; acc.z += w * xv.z; acc.w += w * xv.w;
  }
  part[r][s4 * 4 + 0] = acc.x;
  part[r][s4 * 4 + 1] = acc.y;
  part[r][s4 * 4 + 2] = acc.z;
  part[r][s4 * 4 + 3] = acc.w;
  __syncthreads();
  if (t < S) {
    float smv = 0.f;
#pragma unroll
    for (int rr2 = 0; rr2 < 16; ++rr2) smv += part[rr2][t];
    out[b * S + t] = smv;
  }
}

extern "C" void kernel_launch(void* const* d_in, const int* in_sizes, int n_in,
                              void* d_out, int out_size, void* d_ws, size_t ws_size,
                              hipStream_t stream) {
  const float* x = (const float*)d_in[0];   // (B, L, S) f32
  const float* W = (const float*)d_in[1];   // (L, H)   f32
  const float* A = (const float*)d_in[2];   // (HS, HS) f32
  float* out = (float*)d_out;               // (B, S)   f32

  float* ws        = (float*)d_ws;
  float* Eb        = ws;                               // B*H*L   = 131072
  float* Zb        = Eb + (size_t)B * H * L;           // B*H*L   = 131072
  float* partial_q = Zb + (size_t)B * H * L;           // B*16*HS = 131072
  float* partial_v = partial_q + (size_t)B * 16 * HS;  // B*16*HS = 131072
  float* u_pad     = partial_v + (size_t)B * 16 * HS;  // B*H*2L  = 262144
  float* partial_s = u_pad + (size_t)B * H * 2 * L;    // B*8*L   = 131072
  unsigned* counters = (unsigned*)(partial_s + (size_t)B * 8 * L);  // 72 slots x 64B
  // total ≈ 3.5 MB of d_ws

  kA_prep_qpart<<<dim3(B, 16), 512, 0, stream>>>(W, x, Eb, Zb, partial_q, counters);
  kB_v         <<<dim3(8, 16), 512, 0, stream>>>(partial_q, Zb, A, partial_v);
  kC_u         <<<dim3(B, 16), 512, 0, stream>>>(x, partial_v, u_pad);
  kDF_out      <<<dim3(B, 72), 512, 0, stream>>>(x, u_pad, Eb, Zb, partial_s, counters, out);
}

// Round 16
// 52.007 us; speedup vs baseline: 2.0720x; 2.0720x over previous
//
#include <hip/hip_runtime.h>

#define L 2048
#define H 8
#define S 128
#define B 8
#define HS 1024

// ============ KA: fused {per-b E,Z prefix-scan} + partial_q ============
// grid (B, 16) = 128 blocks x 512 threads. j-chunks of 128.
__global__ __launch_bounds__(512) void kA_prep_qpart(const float* __restrict__ W,
                                                     const float* __restrict__ x,
                                                     float* __restrict__ Eb,
                                                     float* __restrict__ Zb,
                                                     float* __restrict__ partial_q,
                                                     unsigned* __restrict__ counters) {
  const int b = blockIdx.x, jc = blockIdx.y;
  const int t = threadIdx.x;
  if (b == 0 && jc == 0 && t < 8) counters[t] = 0u;   // kF last-block gate

  __shared__ float ew[128][H];       // 4 KB
  __shared__ float part[16][H][S];   // 64 KB
  __shared__ float tot[512];         // 2 KB

  const int base = jc * 128;
  const int dhi = L - 1 - base;
#pragma unroll
  for (int k = 0; k < 2; ++k) {
    const int idx = t + k * 512;     // [0,1024): i = idx>>3, h = idx&7
    const int i = idx >> 3, h = idx & 7;
    ew[i][h] = expf(W[(size_t)(dhi - i) * H + h]);
  }

  // --- per-b full prefix scan for one h (8 blocks per b) ---
  if (jc < H) {
    const int h = jc;
    const int d0 = t * 4;
    float e[4];
    float run = 0.f;
#pragma unroll
    for (int k = 0; k < 4; ++k) {
      float v = expf(W[(size_t)(d0 + k) * H + h]);
      e[k] = v; run += v;
    }
    tot[t] = run;
    __syncthreads();
    for (int off = 1; off < 512; off <<= 1) {
      float v = (t >= off) ? tot[t - off] : 0.f;
      __syncthreads();
      tot[t] += v;
      __syncthreads();
    }
    float c = (t == 0) ? 0.f : tot[t - 1];
    const size_t ebase = (size_t)(b * H + h) * L;
#pragma unroll
    for (int k = 0; k < 4; ++k) {
      c += e[k];
      Eb[ebase + d0 + k] = e[k];
      Zb[ebase + d0 + k] = c;
    }
  }
  __syncthreads();   // ew ready (and scan done)

  // --- partial_q main loop: 16 row-groups x 8 rows each ---
  const int s4 = t & 31;
  const int r = t >> 5;              // 0..15
  const float4* __restrict__ x4 = (const float4*)(x + (size_t)b * L * S);
  float4 acc[H];
#pragma unroll
  for (int h = 0; h < H; ++h) acc[h] = make_float4(0.f, 0.f, 0.f, 0.f);
#pragma unroll
  for (int k = 0; k < 8; ++k) {
    const int ll = k * 16 + r;
    const int l = base + ll;
    const float4 xv = x4[(size_t)l * 32 + s4];
#pragma unroll
    for (int h = 0; h < H; ++h) {
      const float w = ew[ll][h];
      acc[h].x += w * xv.x; acc[h].y += w * xv.y;
      acc[h].z += w * xv.z; acc[h].w += w * xv.w;
    }
  }
#pragma unroll
  for (int h = 0; h < H; ++h) {
    part[r][h][s4 * 4 + 0] = acc[h].x;
    part[r][h][s4 * 4 + 1] = acc[h].y;
    part[r][h][s4 * 4 + 2] = acc[h].z;
    part[r][h][s4 * 4 + 3] = acc[h].w;
  }
  __syncthreads();
#pragma unroll
  for (int k = 0; k < 2; ++k) {
    const int idx = t + k * 512;           // h*S + s
    const int h = idx >> 7, s = idx & 127;
    float sm = 0.f;
#pragma unroll
    for (int rr = 0; rr < 16; ++rr) sm += part[rr][h][s];
    partial_q[((size_t)b * 16 + jc) * HS + idx] = sm;
  }
}

// ============ KB: all-batch GEMV over one A-chunk ============
// grid (8 ec, 16 dc) = 128 blocks x 512 threads.
__global__ __launch_bounds__(512) void kB_v(const float* __restrict__ partial_q,
                                            const float* __restrict__ Zb,
                                            const float* __restrict__ A,
                                            float* __restrict__ partial_v) {
  const int ebase = blockIdx.x * 128;
  const int dc = blockIdx.y;
  const int dbase = dc * 64;
  const int t = threadIdx.x;
  __shared__ float ql[8][64];
  __shared__ float p2[4][8][128];
  const float invZ = 1.f / Zb[(size_t)(dc >> 1) * L + (L - 1)];   // b=0 copy; h = dc>>1
  {
    const int bb = t >> 6, dl = t & 63;    // 512 = 8 b x 64 d
    const float* __restrict__ pq = partial_q + ((size_t)bb * 16) * HS + dbase + dl;
    float a0 = 0.f, a1 = 0.f, a2 = 0.f, a3 = 0.f;
#pragma unroll
    for (int j4 = 0; j4 < 16; j4 += 4) {
      a0 += pq[(size_t)(j4 + 0) * HS];
      a1 += pq[(size_t)(j4 + 1) * HS];
      a2 += pq[(size_t)(j4 + 2) * HS];
      a3 += pq[(size_t)(j4 + 3) * HS];
    }
    ql[bb][dl] = ((a0 + a1) + (a2 + a3)) * invZ;
  }
  __syncthreads();
  const int el = t & 127, dg = t >> 7;     // 4 d-groups of 16
  const int e = ebase + el;
  const float* __restrict__ Ab = A + (size_t)(dbase + dg * 16) * HS + e;
  float acc[8] = {0.f, 0.f, 0.f, 0.f, 0.f, 0.f, 0.f, 0.f};
#pragma unroll 4
  for (int dd = 0; dd < 16; ++dd) {
    const float a = Ab[(size_t)dd * HS];
    const int d = dg * 16 + dd;
    acc[0] += ql[0][d] * a;
    acc[1] += ql[1][d] * a;
    acc[2] += ql[2][d] * a;
    acc[3] += ql[3][d] * a;
    acc[4] += ql[4][d] * a;
    acc[5] += ql[5][d] * a;
    acc[6] += ql[6][d] * a;
    acc[7] += ql[7][d] * a;
  }
#pragma unroll
  for (int bb = 0; bb < 8; ++bb) p2[dg][bb][el] = acc[bb];
  __syncthreads();
#pragma unroll
  for (int k = 0; k < 2; ++k) {
    const int idx = t + k * 512;        // [0,1024): bb = idx>>7, el2 = idx&127
    const int bb = idx >> 7, el2 = idx & 127;
    partial_v[((size_t)bb * 16 + dc) * HS + ebase + el2] =
        (p2[0][bb][el2] + p2[1][bb][el2]) + (p2[2][bb][el2] + p2[3][bb][el2]);
  }
}

// ============ KC: fused v-reduce + u ============
// grid (B, 16) = 128 blocks x 512 threads -> XCD b. j-chunks of 128.
__global__ __launch_bounds__(512) void kC_u(const float* __restrict__ x,
                                            const float* __restrict__ partial_v,
                                            float* __restrict__ u_pad) {
  const int b = blockIdx.x, jc = blockIdx.y;
  const int t = threadIdx.x;
  __shared__ float vs[HS];
  __shared__ float up[4][H][128];
#pragma unroll
  for (int k = 0; k < 2; ++k) {
    const int i = t + k * 512;
    float a0 = 0.f, a1 = 0.f, a2 = 0.f, a3 = 0.f;
#pragma unroll
    for (int dcc = 0; dcc < 16; dcc += 4) {
      a0 += partial_v[((size_t)b * 16 + dcc + 0) * HS + i];
      a1 += partial_v[((size_t)b * 16 + dcc + 1) * HS + i];
      a2 += partial_v[((size_t)b * 16 + dcc + 2) * HS + i];
      a3 += partial_v[((size_t)b * 16 + dcc + 3) * HS + i];
    }
    vs[i] = (a0 + a1) + (a2 + a3);
  }
  __syncthreads();
  const int jl = t & 127, sq = t >> 7;
  const int j = jc * 128 + jl;
  const float4* __restrict__ xr = (const float4*)(x + ((size_t)b * L + j) * S) + sq * 8;
  float4 xv[8];
#pragma unroll
  for (int i = 0; i < 8; ++i) xv[i] = xr[i];
  float acc[H];
#pragma unroll
  for (int h = 0; h < H; ++h) {
    const float4* __restrict__ vv = (const float4*)(vs + h * S + sq * 32);
    float a = 0.f;
#pragma unroll
    for (int i = 0; i < 8; ++i) {
      const float4 w = vv[i];   // same addr across 128-lane group -> LDS broadcast
      a += xv[i].x * w.x + xv[i].y * w.y + xv[i].z * w.z + xv[i].w * w.w;
    }
    acc[h] = a;
  }
#pragma unroll
  for (int h = 0; h < H; ++h) up[sq][h][jl] = acc[h];
  __syncthreads();
#pragma unroll
  for (int k = 0; k < 2; ++k) {
    const int idx = t + k * 512;       // [0,1024): h = idx>>7, j2 = idx&127
    const int h = idx >> 7, j2 = idx & 127;
    const float sv = (up[0][h][j2] + up[1][h][j2]) + (up[2][h][j2] + up[3][h][j2]);
    const size_t rowbase = (size_t)(b * H + h) * (2 * L);
    u_pad[rowbase + jc * 128 + j2] = 0.f;        // zero pad (front half)
    u_pad[rowbase + L + jc * 128 + j2] = sv;
  }
}

// ============ KD: conv partials with LDS-staged u-window ============
// grid (B, 72) = 576 blocks x 512 threads -> batch b pinned to XCD b.
// Block (b, rr->(lt,dtt)): l in [lt*128,+128), d in [dtt*256,+256).
// u-window [l0-dtt*256-384, +512) staged to LDS once (zero-pad covers negatives);
// slide loop reads LDS (ds_read_b128) instead of global.
__global__ __launch_bounds__(512) void kD_conv(const float* __restrict__ u_pad,
                                               const float* __restrict__ Eb,
                                               const float* __restrict__ Zb,
                                               float* __restrict__ partial_s) {
  const int b = blockIdx.x;
  const int rr = blockIdx.y;
  int lt = 0, c = 0;
  while (c + (lt / 2 + 1) <= rr) { c += lt / 2 + 1; ++lt; }
  const int dtt = rr - c;
  const int l0 = lt * 128;
  const int t = threadIdx.x;
  const int tsub = t & 31;
  const int h = (t >> 5) & 7;
  const int dh = t >> 8;

  __shared__ float u_win[H][512];     // 16 KB
  __shared__ float sred[2][H][128];   // 8 KB

  // --- stage u-window: w0 = l0 - dtt*256 - 384 (multiple of 4); 1024 float4 loads ---
  const int w0 = l0 - dtt * 256 - 384;
#pragma unroll
  for (int k = 0; k < 2; ++k) {
    const int idx = t + k * 512;          // [0,1024): hh = idx>>7, i4 = idx&127
    const int hh = idx >> 7, i4 = idx & 127;
    const float4 v = *(const float4*)(u_pad + (size_t)(b * H + hh) * (2 * L) + L + w0 + i4 * 4);
    *(float4*)&u_win[hh][i4 * 4] = v;
  }
  __syncthreads();

  const int dbase = dtt * 256 + dh * 128;
  const int Lb = l0 + tsub * 4;
  // LDS base index for this thread: (Lb - dbase - 8) - w0 = tsub*4 - dh*128 + 376
  const int lb0 = tsub * 4 - dh * 128 + 376;
  const float4* __restrict__ Eh4 = (const float4*)(Eb + (size_t)(b * H + h) * L);
  float acc0 = 0.f, acc1 = 0.f, acc2 = 0.f, acc3 = 0.f;
  float4 lo = *(const float4*)&u_win[h][lb0 + 4];   // u[Lb - dbase - 4]
  float4 hi = *(const float4*)&u_win[h][lb0 + 8];   // u[Lb - dbase]
#pragma unroll 4
  for (int dd = 0; dd < 128; dd += 4) {
    const int d0 = dbase + dd;
    const float4 ev  = Eh4[d0 >> 2];                      // wave-uniform -> scalar load
    const float4 nlo = *(const float4*)&u_win[h][lb0 - dd];   // u[Lb - d0 - 8]
    acc0 += ev.x * hi.x; acc1 += ev.x * hi.y; acc2 += ev.x * hi.z; acc3 += ev.x * hi.w;
    acc0 += ev.y * lo.w; acc1 += ev.y * hi.x; acc2 += ev.y * hi.y; acc3 += ev.y * hi.z;
    acc0 += ev.z * lo.z; acc1 += ev.z * lo.w; acc2 += ev.z * hi.x; acc3 += ev.z * hi.y;
    acc0 += ev.w * lo.y; acc1 += ev.w * lo.z; acc2 += ev.w * lo.w; acc3 += ev.w * hi.x;
    hi = lo; lo = nlo;
  }
  const float4 zv = *(const float4*)&Zb[(size_t)(b * H + h) * L + Lb];
  sred[dh][h][tsub * 4 + 0] = acc0 / zv.x;
  sred[dh][h][tsub * 4 + 1] = acc1 / zv.y;
  sred[dh][h][tsub * 4 + 2] = acc2 / zv.z;
  sred[dh][h][tsub * 4 + 3] = acc3 / zv.w;
  __syncthreads();
  if (t < 128) {
    float sc = 0.f;
#pragma unroll
    for (int hh = 0; hh < H; ++hh) sc += sred[0][hh][t] + sred[1][hh][t];
    partial_s[((size_t)b * 8 + dtt) * L + l0 + t] = sc;
  }
}

// ============ KF: redundant softmax + 128-l weighted-sum chunk + last-block reduce ============
// grid (B, 16) = 128 blocks x 512 threads -> XCD b.
__global__ __launch_bounds__(512) void kF_out(const float* __restrict__ x,
                                              const float* __restrict__ partial_s,
                                              float* __restrict__ partial,
                                              unsigned* __restrict__ counters,
                                              float* __restrict__ out) {
  const int b = blockIdx.x, c = blockIdx.y;
  const int t = threadIdx.x;
  __shared__ float ep[L];          // 8 KB
  __shared__ float red[512];       // 2 KB
  __shared__ float part[16][S];    // 8 KB

  // --- Phase A: scores -> softmax weights (thread t owns l in [4t, 4t+4)) ---
  const int l0 = t * 4;
  const int ltq = t >> 6;                // (4t)>>8 = floor(lt/2)
  float sc[4] = {0.f, 0.f, 0.f, 0.f};
  for (int dtt = 0; dtt <= ltq; ++dtt) {
    const float4 a = *(const float4*)(partial_s + ((size_t)b * 8 + dtt) * L + l0);
    sc[0] += a.x; sc[1] += a.y; sc[2] += a.z; sc[3] += a.w;
  }
  if (t == 511) sc[3] = -3.4e38f;        // l = 2047 excluded
  float mx = fmaxf(fmaxf(sc[0], sc[1]), fmaxf(sc[2], sc[3]));
  red[t] = mx;
  __syncthreads();
  for (int off = 256; off > 0; off >>= 1) {
    if (t < off) red[t] = fmaxf(red[t], red[t + off]);
    __syncthreads();
  }
  mx = red[0];
  __syncthreads();
  float e[4];
  float sm = 0.f;
#pragma unroll
  for (int k = 0; k < 4; ++k) {
    e[k] = (l0 + k < L - 1) ? expf(sc[k] - mx) : 0.f;
    sm += e[k];
  }
  red[t] = sm;
  __syncthreads();
  for (int off = 256; off > 0; off >>= 1) {
    if (t < off) red[t] += red[t + off];
    __syncthreads();
  }
  const float inv = 1.f / red[0];
#pragma unroll
  for (int k = 0; k < 4; ++k) ep[l0 + k] = e[k] * inv;
  __syncthreads();

  // --- Phase B: partial[b,c,s] = sum_{l in 128-chunk c} ep[l] * x[b,l,s] ---
  const int s4 = t & 31;
  const int r = t >> 5;                  // 16 row-groups of 8 l
  const int base = c * 128;
  const float4* __restrict__ x4 = (const float4*)(x + (size_t)b * L * S);
  float4 acc = make_float4(0.f, 0.f, 0.f, 0.f);
#pragma unroll
  for (int k = 0; k < 8; ++k) {
    const int l = base + k * 16 + r;
    const float w = ep[l];
    const float4 xv = x4[(size_t)l * 32 + s4];
    acc.x += w * xv.x; acc.y += w * xv.y; acc.z += w * xv.z; acc.w += w * xv.w;
  }
  part[r][s4 * 4 + 0] = acc.x;
  part[r][s4 * 4 + 1] = acc.y;
  part[r][s4 * 4 + 2] = acc.z;
  part[r][s4 * 4 + 3] = acc.w;
  __syncthreads();
  if (t < S) {
    float smv = 0.f;
#pragma unroll
    for (int rr = 0; rr < 16; ++rr) smv += part[rr][t];
    partial[((size_t)b * 16 + c) * S + t] = smv;
  }
  // --- last-block gate (one-shot, 128 blocks — proven-cheap scale) ---
  __threadfence();
  __syncthreads();
  __shared__ unsigned lastFlag;
  if (t == 0)
    lastFlag = (atomicAdd(&counters[0], 1u) == (unsigned)(B * 16 - 1)) ? 1u : 0u;
  __syncthreads();
  if (lastFlag) {
#pragma unroll
    for (int k = 0; k < 2; ++k) {
      const int idx = t + k * 512;          // b2 = idx>>7, s = idx&127
      const int b2 = idx >> 7, s = idx & 127;
      float a = 0.f;
#pragma unroll 4
      for (int cc = 0; cc < 16; ++cc) a += partial[((size_t)b2 * 16 + cc) * S + s];
      out[b2 * S + s] = a;
    }
  }
}

extern "C" void kernel_launch(void* const* d_in, const int* in_sizes, int n_in,
                              void* d_out, int out_size, void* d_ws, size_t ws_size,
                              hipStream_t stream) {
  const float* x = (const float*)d_in[0];   // (B, L, S) f32
  const float* W = (const float*)d_in[1];   // (L, H)   f32
  const float* A = (const float*)d_in[2];   // (HS, HS) f32
  float* out = (float*)d_out;               // (B, S)   f32

  float* ws        = (float*)d_ws;
  float* Eb        = ws;                               // B*H*L   = 131072
  float* Zb        = Eb + (size_t)B * H * L;           // B*H*L   = 131072
  float* partial_q = Zb + (size_t)B * H * L;           // B*16*HS = 131072
  float* partial_v = partial_q + (size_t)B * 16 * HS;  // B*16*HS = 131072
  float* u_pad     = partial_v + (size_t)B * 16 * HS;  // B*H*2L  = 262144
  float* partial_s = u_pad + (size_t)B * H * 2 * L;    // B*8*L   = 131072
  float* partial   = partial_s + (size_t)B * 8 * L;    // B*16*S  = 16384
  unsigned* counters = (unsigned*)(partial + (size_t)B * 16 * S);
  // total ≈ 3.7 MB of d_ws

  kA_prep_qpart<<<dim3(B, 16), 512, 0, stream>>>(W, x, Eb, Zb, partial_q, counters);
  kB_v         <<<dim3(8, 16), 512, 0, stream>>>(partial_q, Zb, A, partial_v);
  kC_u         <<<dim3(B, 16), 512, 0, stream>>>(x, partial_v, u_pad);
  kD_conv      <<<dim3(B, 72), 512, 0, stream>>>(u_pad, Eb, Zb, partial_s);
  kF_out       <<<dim3(B, 16), 512, 0, stream>>>(x, partial_s, partial, counters, out);
}